// Round 5
// baseline (403.224 us; speedup 1.0000x reference)
//
#include <hip/hip_runtime.h>
#include <math.h>

#define B_ 4
#define N_ 2048
#define M_ 1024
#define K_ 32
#define HEADS_ 4
#define NH_ 128
#define PI_F 3.14159265358979323846f

typedef unsigned long long ull;
typedef __attribute__((ext_vector_type(8))) _Float16 half8;
typedef __attribute__((ext_vector_type(4))) _Float16 half4v;
typedef __attribute__((ext_vector_type(2))) _Float16 half2v;
typedef __attribute__((ext_vector_type(4))) float f32x4;

// workspace offsets (in floats)
#define OFF_WGW   0            // 128*128
#define OFF_W2    16384        // 130*256  [WB | WG]
#define OFF_CB    49664        // 128
#define OFF_CGV   49792        // 128
#define OFF_WVOT  49920        // 12*128
#define OFF_OUTC  51456        // 4
#define OFF_KW    51460        // B*M*4*132
#define OFF_KB    2214148      // B*M*4
#define OFF_VF    2230532      // B*M*128
#define OFF_BASE  2754820      // B*M*128
#define OFF_W2F   3279108      // 40960 halfs = 20480 floats (W2^T MFMA A-frags)
#define OFF_WV1F  3299588      // 16384 halfs = 8192 floats  (wv1^T MFMA A-frags)
#define OFF_U     3307780      // 130*256 = 33280
#define OFF_E     3341060      // 256
#define OFF_WQK   3341316      // 128*524 = 67072  [kw 520 | kb 4] per l row
#define OFF_KWCC  3408388      // 524 consts
// total = 3408912 floats (~13.6 MB)

// ---------- precompute stage A: WGW | U | E ----------
__global__ void enf_preA(const float* __restrict__ w3v, const float* __restrict__ wv1,
                         const float* __restrict__ w2q, const float* __restrict__ w3q,
                         const float* __restrict__ b2q, const float* __restrict__ b3q,
                         float* __restrict__ WGW, float* __restrict__ U,
                         float* __restrict__ E) {
  const int blk = blockIdx.x, tid = threadIdx.x;
  if (blk < 64) {
    int o = blk*256 + tid;
    int i = o >> 7, j = o & 127;
    float acc = 0.f;
    for (int r = 0; r < 128; ++r) acc = fmaf(w3v[i*256 + 128 + r], wv1[r*128 + j], acc);
    WGW[o] = acc;
  } else if (blk < 194) {
    int a = blk - 64, s = tid;
    float acc = 0.f;
    for (int i = 0; i < 128; ++i) acc = fmaf(w2q[a*128 + i], w3q[i*256 + s], acc);
    U[a*256 + s] = acc;
  } else {
    int s = tid;
    float acc = b3q[s];
    for (int j = 0; j < 128; ++j) acc = fmaf(b2q[j], w3q[j*256 + s], acc);
    E[s] = acc;
  }
}

// ---------- precompute stage B: W2 | consts | WQK | kwcc ----------
__global__ void enf_preB(const float* __restrict__ w2v, const float* __restrict__ w3v,
                         const float* __restrict__ WGW, const float* __restrict__ U,
                         const float* __restrict__ E, const float* __restrict__ wk,
                         const float* __restrict__ bk,
                         const float* __restrict__ b2v, const float* __restrict__ b3v,
                         const float* __restrict__ wv1, const float* __restrict__ bv1,
                         const float* __restrict__ wv2, const float* __restrict__ wout,
                         const float* __restrict__ bv2, const float* __restrict__ bout,
                         float* __restrict__ W2, float* __restrict__ cb,
                         float* __restrict__ cgv, float* __restrict__ wvoT,
                         float* __restrict__ outconst, float* __restrict__ WQK,
                         float* __restrict__ kwcc) {
  const int blk = blockIdx.x, t = threadIdx.x;
  if (blk < 130) {
    int a = blk, j = t;
    float acc = 0.f;
    if (j < 128) {
      for (int i = 0; i < 128; ++i) acc = fmaf(w2v[a*128 + i], w3v[i*256 + j], acc);
    } else {
      int j2 = j - 128;
      for (int i = 0; i < 128; ++i) acc = fmaf(w2v[a*128 + i], WGW[i*128 + j2], acc);
    }
    W2[a*256 + j] = acc;
  } else if (blk == 130) {
    if (t < 128) {
      float a1 = 0.f;
      for (int i = 0; i < 128; ++i) a1 = fmaf(b2v[i], w3v[i*256 + t], a1);
      cb[t] = a1 + b3v[t];
      float a2 = 0.f;
      for (int i = 0; i < 128; ++i) a2 = fmaf(b2v[i], WGW[i*128 + t], a2);
      for (int r = 0; r < 128; ++r) a2 = fmaf(b3v[128 + r], wv1[r*128 + t], a2);
      cgv[t] = a2 + bv1[t];
    }
    for (int o = t; o < 1536; o += 256) {
      int r12 = o >> 7, i = o & 127;
      int h = r12 / 3, c = r12 - h*3;
      float acc = 0.f;
      for (int k = 0; k < 128; ++k)
        acc = fmaf(wv2[i*512 + h*128 + k], wout[(h*128 + k)*3 + c], acc);
      wvoT[r12*128 + i] = acc;
    }
    if (t < 3) {
      float acc = bout[t];
      for (int r = 0; r < 512; ++r) acc = fmaf(bv2[r], wout[r*3 + t], acc);
      outconst[t] = acc;
    }
  } else if (blk < 259) {
    int l = blk - 131;
    for (int col = t; col < 524; col += 256) {
      float acc = 0.f;
      if (col < 520) {
        int h = col / 130, a = col - h*130;
        const float* ur = U + a*256 + h*64;
        const float* wr = wk + l*256 + h*64;
        for (int q = 0; q < 64; ++q) acc = fmaf(ur[q], wr[q], acc);
      } else {
        int h = col - 520;
        const float* er = E + h*64;
        const float* wr = wk + l*256 + h*64;
        for (int q = 0; q < 64; ++q) acc = fmaf(er[q], wr[q], acc);
      }
      WQK[l*524 + col] = acc;
    }
  } else {
    for (int col = t; col < 524; col += 256) {
      float acc = 0.f;
      if (col < 520) {
        int h = col / 130, a = col - h*130;
        const float* ur = U + a*256 + h*64;
        const float* br = bk + h*64;
        for (int q = 0; q < 64; ++q) acc = fmaf(ur[q], br[q], acc);
      } else {
        int h = col - 520;
        const float* er = E + h*64;
        const float* br = bk + h*64;
        for (int q = 0; q < 64; ++q) acc = fmaf(er[q], br[q], acc);
      }
      kwcc[col] = acc;
    }
  }
}

// ---------- precompute stage C: MFMA A-fragments ----------
__global__ void enf_preC(const float* __restrict__ W2, const float* __restrict__ wv1,
                         _Float16* __restrict__ W2f, _Float16* __restrict__ wv1f) {
  const int blk = blockIdx.x, tid = threadIdx.x;
  if (blk < 160) {
    int idx = blk*256 + tid;
    int i = idx & 7, lane = (idx >> 3) & 63;
    int rest = idx >> 9;
    int ks = rest % 5, mt = rest / 5;
    int k = ks*32 + ((lane >> 4) << 3) + i;
    int n = mt*16 + (lane & 15);
    W2f[idx] = (k < 130) ? (_Float16)W2[k*256 + n] : (_Float16)0.f;
  } else {
    int idx = (blk - 160)*256 + tid;
    int i = idx & 7, lane = (idx >> 3) & 63;
    int rest = idx >> 9;
    int ks = rest & 3, mt = rest >> 2;
    int k = ks*32 + ((lane >> 4) << 3) + i;
    int j = mt*16 + (lane & 15);
    wv1f[idx] = (_Float16)wv1[k*128 + j];
  }
}

// ---------- latent kernel: 8 latents per block ----------
__global__ __launch_bounds__(256) void enf_latent(
    const float* __restrict__ c, const float* __restrict__ wvw,
    const float* __restrict__ bv, const float* __restrict__ WQK,
    const float* __restrict__ kwcc, const float* __restrict__ cb,
    const float* __restrict__ wv1,
    float* __restrict__ kw, float* __restrict__ kb,
    float* __restrict__ vf_o, float* __restrict__ base_o) {
  const int bm0 = blockIdx.x * 8;
  const int tid = threadIdx.x;
  __shared__ float cls[8][128];
  __shared__ float evs[8][128];
  for (int t = tid; t < 1024; t += 256) cls[t >> 7][t & 127] = c[(size_t)bm0*128 + t];
  __syncthreads();
  for (int col = tid; col < 652; col += 256) {
    float a[8];
#pragma unroll
    for (int i = 0; i < 8; ++i) a[i] = 0.f;
    if (col < 128) {
      for (int l = 0; l < 128; ++l) {
        float w = wvw[l*128 + col];
#pragma unroll
        for (int i = 0; i < 8; ++i) a[i] = fmaf(cls[i][l], w, a[i]);
      }
      float bvc = bv[col];
      float cbf = 1.f + cb[col];
#pragma unroll
      for (int i = 0; i < 8; ++i) {
        float v = a[i] + bvc;
        vf_o[(size_t)(bm0 + i)*128 + col] = v;
        evs[i][col] = v*cbf;
      }
    } else {
      const float* wq = WQK + (col - 128);
      for (int l = 0; l < 128; ++l) {
        float w = wq[l*524];
#pragma unroll
        for (int i = 0; i < 8; ++i) a[i] = fmaf(cls[i][l], w, a[i]);
      }
      float cc = kwcc[col - 128];
      if (col < 648) {
        int h = (col - 128) / 130, aa = (col - 128) - h*130;
#pragma unroll
        for (int i = 0; i < 8; ++i)
          kw[((size_t)(bm0 + i)*4 + h)*132 + aa] = a[i] + cc;
      } else {
        int h = col - 648;
#pragma unroll
        for (int i = 0; i < 8; ++i)
          kb[(size_t)(bm0 + i)*4 + h] = a[i] + cc;
      }
    }
  }
  __syncthreads();
  {
    const int col = tid & 127, h4 = (tid >> 7) * 4;
    float a0 = 0.f, a1 = 0.f, a2 = 0.f, a3 = 0.f;
    for (int l = 0; l < 128; ++l) {
      float w = wv1[l*128 + col];
      a0 = fmaf(evs[h4 + 0][l], w, a0);
      a1 = fmaf(evs[h4 + 1][l], w, a1);
      a2 = fmaf(evs[h4 + 2][l], w, a2);
      a3 = fmaf(evs[h4 + 3][l], w, a3);
    }
    base_o[(size_t)(bm0 + h4 + 0)*128 + col] = a0;
    base_o[(size_t)(bm0 + h4 + 1)*128 + col] = a1;
    base_o[(size_t)(bm0 + h4 + 2)*128 + col] = a2;
    base_o[(size_t)(bm0 + h4 + 3)*128 + col] = a3;
  }
}

// sfv B-fragment position: [nt(2)][ks(5)][lane(64)][i(8)] halfs
__device__ __forceinline__ int fragpos(int k, int e) {
  return ((((e >> 4)*5 + (k >> 5))*64 + (((k >> 3) & 3) << 4) + (e & 15)) << 3) + (k & 7);
}

// ---------- main kernel: one block per (b,n) ----------
__global__ __launch_bounds__(256, 8) void enf_main(
    const float* __restrict__ x, const float* __restrict__ p,
    const float* __restrict__ g,
    const float* __restrict__ w1q, const float* __restrict__ w1v,
    const _Float16* __restrict__ w2f, const _Float16* __restrict__ wv1f,
    const float* __restrict__ cgv, const float* __restrict__ wvoT,
    const float* __restrict__ outconst,
    const float* __restrict__ kw, const float* __restrict__ kb,
    const float* __restrict__ vf, const float* __restrict__ base,
    float* __restrict__ out) {
  const int bn = blockIdx.x;
  const int b = bn >> 11;          // N = 2048
  const int tid = threadIdx.x;
  const int lane = tid & 63;
  const int wid = tid >> 6;

  // S timeline (bytes):
  //  phase1: sfq fp16 half2[65][32] @ [0,8320) | sfvB 5120 halfs @ [8320,18560)
  //  phase2: evlds half[32][136] @ [0,8704)    | gt fp16 [32][136] @ [8704,17408)
  //  phase3: poL fp32 [384] @ [0,1536)
  __shared__ alignas(16) float S[4640];
  __shared__ int   selm[K_];
  __shared__ float seld[K_];
  __shared__ float gkv[K_];
  __shared__ float bi0[K_], bi1[K_];
  __shared__ float logits_s[K_*HEADS_];
  __shared__ float hpart[HEADS_*4];

  float* candd = S;
  int*   candm = (int*)(S + 128);
  half2v* sfq2 = (half2v*)S;                 // [65][32] half2 words
  _Float16* sfvB = (_Float16*)(S + 2080);    // 5120 halfs
  _Float16* evlds = (_Float16*)S;            // [32][136]
  _Float16* gt_h  = (_Float16*)S + 4352;     // [32][136]
  float* poL   = S;                          // [32][12]

  const float x0 = x[bn*2 + 0];
  const float x1 = x[bn*2 + 1];
  const float2* pb2 = (const float2*)(p + (size_t)b*M_*2);

  // ---- Phase A: per-wave top-32 via binary-search threshold on float bits ----
  unsigned db[4]; int mm[4];
#pragma unroll
  for (int s = 0; s < 4; ++s) {
    int m = wid*256 + s*64 + lane;
    float2 pv = pb2[m];
    float d0 = x0 - pv.x, d1 = x1 - pv.y;
    float d = __fadd_rn(__fmul_rn(d0, d0), __fmul_rn(d1, d1));
    db[s] = __float_as_uint(d);
    mm[s] = m;
  }
  unsigned xth = 0;
  for (int bit = 30; bit >= 0; --bit) {
    unsigned trial = xth | (1u << bit);
    int cnt = __popcll(__ballot(db[0] < trial)) + __popcll(__ballot(db[1] < trial))
            + __popcll(__ballot(db[2] < trial)) + __popcll(__ballot(db[3] < trial));
    if (cnt < 32) xth = trial;
  }
  {
    ull bl[4], be[4];
#pragma unroll
    for (int s = 0; s < 4; ++s) {
      bl[s] = __ballot(db[s] < xth);
      be[s] = __ballot(db[s] == xth);
    }
    int r = __popcll(bl[0]) + __popcll(bl[1]) + __popcll(bl[2]) + __popcll(bl[3]);
    const ull lmask = (1ull << lane) - 1ull;
    int pl = 0, pe = 0;
#pragma unroll
    for (int s = 0; s < 4; ++s) {
      if (db[s] < xth) {
        int pos = pl + __popcll(bl[s] & lmask);
        candd[wid*K_ + pos] = __uint_as_float(db[s]);
        candm[wid*K_ + pos] = mm[s];
      } else if (db[s] == xth) {
        int pos = r + pe + __popcll(be[s] & lmask);
        if (pos < K_) {
          candd[wid*K_ + pos] = __uint_as_float(db[s]);
          candm[wid*K_ + pos] = mm[s];
        }
      }
      pl += __popcll(bl[s]);
      pe += __popcll(be[s]);
    }
  }
  __syncthreads();
  if (tid < 128) {
    float d = candd[tid];
    int m = candm[tid];
    int rank = 0;
    for (int i = 0; i < 128; ++i) {
      float di = candd[i];
      rank += (di < d || (di == d && i < tid)) ? 1 : 0;
    }
    if (rank < K_) { selm[rank] = m; seld[rank] = d; }
  }
  __syncthreads();
  if (tid < K_) {
    int m = selm[tid];
    gkv[tid] = g[(size_t)b*M_ + m];
    float2 pv = pb2[m];
    bi0[tid] = x0 - pv.x;
    bi1[tid] = x1 - pv.y;
  }
  __syncthreads();

  // ---- Phase B: sin features, sfq fp16 half2 words, sfv fp16 B-frags ----
  if (tid < 32) {
    const int e = tid;
    half2v h;
    h[0] = (_Float16)__sinf(bi0[e]);
    h[1] = (_Float16)__sinf(bi1[e]);
    sfq2[e] = h;                      // word 0: k=0,1
    sfvB[fragpos(0, e)] = h[0];
    sfvB[fragpos(1, e)] = h[1];
  }
  for (int t = tid; t < 960; t += 256) {      // zero-pad sfv frags k=130..159
    int k = 130 + (t >> 5), e = t & 31;
    sfvB[fragpos(k, e)] = (_Float16)0.f;
  }
  {
    const int e = tid & 31;
    const int jg = tid >> 5;           // 0..7
    const float s0 = PI_F*(bi0[e] + 1.f), s1 = PI_F*(bi1[e] + 1.f);
#pragma unroll
    for (int t4 = 0; t4 < 4; ++t4) {
      const int J = 2*jg + 16*t4;      // even, covers 0..62
      float eqa = s0*w1q[J]     + s1*w1q[64 + J];
      float eqb = s0*w1q[J + 1] + s1*w1q[64 + J + 1];
      float eva = s0*w1v[J]     + s1*w1v[64 + J];
      float evb = s0*w1v[J + 1] + s1*w1v[64 + J + 1];
      half2v hs, hc;
      hs[0] = (_Float16)__sinf(eqa); hs[1] = (_Float16)__sinf(eqb);
      hc[0] = (_Float16)__cosf(eqa); hc[1] = (_Float16)__cosf(eqb);
      sfq2[(1 + (J >> 1))*32 + e]  = hs;   // k = 2+J, 3+J
      sfq2[(33 + (J >> 1))*32 + e] = hc;   // k = 66+J, 67+J
      sfvB[fragpos(2 + J, e)]  = (_Float16)__sinf(eva);
      sfvB[fragpos(3 + J, e)]  = (_Float16)__sinf(evb);
      sfvB[fragpos(66 + J, e)] = (_Float16)__cosf(eva);
      sfvB[fragpos(67 + J, e)] = (_Float16)__cosf(evb);
    }
  }
  __syncthreads();

  // ---- Phase C: attention logits (waves 0,1); waves 2,3 start GEMM1 ----
  if (tid < 128) {
    const int e = tid >> 2, h = tid & 3;
    const int m = selm[e];
    const float* kwrow = kw + ((size_t)((b*M_ + m)*4 + h))*132;
    float accq = kb[(size_t)(b*M_ + m)*4 + h];
    const float4* kw4 = (const float4*)kwrow;
    const half2v* sq = sfq2 + e;
#pragma unroll 4
    for (int q4 = 0; q4 < 32; ++q4) {
      float4 kv = kw4[q4];
      half2v ha = sq[(2*q4 + 0)*32];
      half2v hb = sq[(2*q4 + 1)*32];
      accq = fmaf((float)ha[0], kv.x, accq);
      accq = fmaf((float)ha[1], kv.y, accq);
      accq = fmaf((float)hb[0], kv.z, accq);
      accq = fmaf((float)hb[1], kv.w, accq);
    }
    {
      half2v ht = sq[64*32];
      accq += (float)ht[0]*kwrow[128] + (float)ht[1]*kwrow[129];
    }
    const float gk = gkv[e];
    logits_s[tid] = accq - seld[e]/(gk*gk);
  }

  // ---- GEMM1 (MFMA): C1T = W2^T @ sfv^T
  f32x4 acc1[4][2];
#pragma unroll
  for (int mi = 0; mi < 4; ++mi)
#pragma unroll
    for (int nt = 0; nt < 2; ++nt) acc1[mi][nt] = (f32x4)0.f;
  {
    const half8* w2f8  = (const half8*)w2f;
    const half8* sfvB8 = (const half8*)sfvB;
#pragma unroll
    for (int ks = 0; ks < 5; ++ks) {
      half8 bf0 = sfvB8[(0*5 + ks)*64 + lane];
      half8 bf1 = sfvB8[(1*5 + ks)*64 + lane];
#pragma unroll
      for (int mi = 0; mi < 4; ++mi) {
        const int mt = (mi < 2) ? (2*wid + mi) : (8 + 2*wid + (mi - 2));
        half8 af = w2f8[(mt*5 + ks)*64 + lane];
        acc1[mi][0] = __builtin_amdgcn_mfma_f32_16x16x32_f16(af, bf0, acc1[mi][0], 0, 0, 0);
        acc1[mi][1] = __builtin_amdgcn_mfma_f32_16x16x32_f16(af, bf1, acc1[mi][1], 0, 0, 0);
      }
    }
  }
  __syncthreads();   // sfq + sfvB dead

  // ---- epilogue: evec (mi 0,1) -> evlds fp16; gterm (mi 2,3) -> registers ----
  f32x4 tg[2][2];
#pragma unroll
  for (int mi = 0; mi < 2; ++mi) {
    const int j0 = (2*wid + mi)*16 + ((lane >> 4) << 2);
#pragma unroll
    for (int nt = 0; nt < 2; ++nt) {
      const int e = nt*16 + (lane & 15);
      const float4 v4 = *(const float4*)(vf + ((size_t)(b*M_ + selm[e]))*NH_ + j0);
      f32x4 a = acc1[mi][nt];
      half4v hv;
      hv[0] = (_Float16)(v4.x * a[0]);
      hv[1] = (_Float16)(v4.y * a[1]);
      hv[2] = (_Float16)(v4.z * a[2]);
      hv[3] = (_Float16)(v4.w * a[3]);
      *(half4v*)(evlds + e*136 + j0) = hv;
    }
  }
#pragma unroll
  for (int mi = 0; mi < 2; ++mi) {
    const int j0 = 32*wid + mi*16 + ((lane >> 4) << 2);
    const float4 c4 = *(const float4*)(cgv + j0);
#pragma unroll
    for (int nt = 0; nt < 2; ++nt) {
      const int e = nt*16 + (lane & 15);
      const float4 b4 = *(const float4*)(base + ((size_t)(b*M_ + selm[e]))*NH_ + j0);
      f32x4 a = acc1[2 + mi][nt];
      tg[mi][nt][0] = a[0] + b4.x + c4.x;
      tg[mi][nt][1] = a[1] + b4.y + c4.y;
      tg[mi][nt][2] = a[2] + b4.z + c4.z;
      tg[mi][nt][3] = a[3] + b4.w + c4.w;
    }
  }
  __syncthreads();

  // ---- GEMM2 (MFMA): acc = tg + wv1^T @ ev^T ----
  {
    const half8* wv1f8 = (const half8*)wv1f;
    const half8* evB   = (const half8*)evlds;   // index: e*17 + ks*4 + (lane>>4)
#pragma unroll
    for (int ks = 0; ks < 4; ++ks) {
      half8 bf0 = evB[(lane & 15)*17 + ks*4 + (lane >> 4)];
      half8 bf1 = evB[(16 + (lane & 15))*17 + ks*4 + (lane >> 4)];
#pragma unroll
      for (int mi = 0; mi < 2; ++mi) {
        half8 af = wv1f8[((2*wid + mi)*4 + ks)*64 + lane];
        tg[mi][0] = __builtin_amdgcn_mfma_f32_16x16x32_f16(af, bf0, tg[mi][0], 0, 0, 0);
        tg[mi][1] = __builtin_amdgcn_mfma_f32_16x16x32_f16(af, bf1, tg[mi][1], 0, 0, 0);
      }
    }
  }
  // gelu epilogue -> gt fp16 (disjoint from evlds; no barrier needed)
#pragma unroll
  for (int mi = 0; mi < 2; ++mi) {
    const int j0 = (2*wid + mi)*16 + ((lane >> 4) << 2);
#pragma unroll
    for (int nt = 0; nt < 2; ++nt) {
      const int e = nt*16 + (lane & 15);
      f32x4 a = tg[mi][nt];
      half4v gv;
#pragma unroll
      for (int jj = 0; jj < 4; ++jj) {
        float tval = a[jj];
        float u = 0.79788456080286536f*(tval + 0.044715f*tval*tval*tval);
        float ex = __expf(2.f*u);
        float th = 1.f - 2.f/(ex + 1.f);
        gv[jj] = (_Float16)(0.5f*tval*(1.f + th));
      }
      *(half4v*)(gt_h + e*136 + j0) = gv;
    }
  }
  __syncthreads();

  // ---- Phase F: po[e][12] = gt[e] @ wvoT^T ----
  for (int t = tid; t < K_*12; t += 256) {
    const int e = t / 12, r = t - (t/12)*12;
    const float4* wr4 = (const float4*)(wvoT + r*NH_);
    const half8* gr8 = (const half8*)(gt_h + e*136);
    float a0 = 0.f, a1 = 0.f, a2 = 0.f, a3 = 0.f;
#pragma unroll 4
    for (int q = 0; q < 16; ++q) {
      half8 gq = gr8[q];
      float4 w0 = wr4[2*q], w1 = wr4[2*q + 1];
      a0 = fmaf((float)gq[0], w0.x, a0);
      a1 = fmaf((float)gq[1], w0.y, a1);
      a2 = fmaf((float)gq[2], w0.z, a2);
      a3 = fmaf((float)gq[3], w0.w, a3);
      a0 = fmaf((float)gq[4], w1.x, a0);
      a1 = fmaf((float)gq[5], w1.y, a1);
      a2 = fmaf((float)gq[6], w1.z, a2);
      a3 = fmaf((float)gq[7], w1.w, a3);
    }
    poL[t] = (a0 + a1) + (a2 + a3);
  }
  __syncthreads();

  // ---- Phase G: softmax over K per head + combine ----
  if (tid < 128) {
    const int h = tid >> 5, e = tid & 31;
    float l = logits_s[e*4 + h];
    float mx = l;
#pragma unroll
    for (int off = 1; off < 32; off <<= 1) mx = fmaxf(mx, __shfl_xor(mx, off));
    float w = __expf(l - mx);
    float s = w;
#pragma unroll
    for (int off = 1; off < 32; off <<= 1) s += __shfl_xor(s, off);
    float att = w / s;
    float p0 = att * poL[e*12 + h*3 + 0];
    float p1 = att * poL[e*12 + h*3 + 1];
    float p2 = att * poL[e*12 + h*3 + 2];
#pragma unroll
    for (int off = 1; off < 32; off <<= 1) {
      p0 += __shfl_xor(p0, off);
      p1 += __shfl_xor(p1, off);
      p2 += __shfl_xor(p2, off);
    }
    if (e == 0) { hpart[h*4 + 0] = p0; hpart[h*4 + 1] = p1; hpart[h*4 + 2] = p2; }
  }
  __syncthreads();
  if (tid < 3) {
    out[(size_t)bn*3 + tid] = outconst[tid]
        + hpart[0*4 + tid] + hpart[1*4 + tid] + hpart[2*4 + tid] + hpart[3*4 + tid];
  }
}

extern "C" void kernel_launch(void* const* d_in, const int* in_sizes, int n_in,
                              void* d_out, int out_size, void* d_ws, size_t ws_size,
                              hipStream_t stream) {
  (void)in_sizes; (void)n_in; (void)out_size; (void)ws_size;
  const float* x    = (const float*)d_in[0];
  const float* p    = (const float*)d_in[1];
  const float* c    = (const float*)d_in[2];
  const float* g    = (const float*)d_in[3];
  const float* w1q  = (const float*)d_in[4];
  const float* w2q  = (const float*)d_in[5];
  const float* b2q  = (const float*)d_in[6];
  const float* w3q  = (const float*)d_in[7];
  const float* b3q  = (const float*)d_in[8];
  const float* w1v  = (const float*)d_in[9];
  const float* w2v  = (const float*)d_in[10];
  const float* b2v  = (const float*)d_in[11];
  const float* w3v  = (const float*)d_in[12];
  const float* b3v  = (const float*)d_in[13];
  const float* wk   = (const float*)d_in[14];
  const float* bk   = (const float*)d_in[15];
  const float* wvw  = (const float*)d_in[16];
  const float* bv   = (const float*)d_in[17];
  const float* wv1  = (const float*)d_in[18];
  const float* bv1  = (const float*)d_in[19];
  const float* wv2  = (const float*)d_in[20];
  const float* bv2  = (const float*)d_in[21];
  const float* wout = (const float*)d_in[22];
  const float* bout = (const float*)d_in[23];
  float* ws = (float*)d_ws;
  float* outp = (float*)d_out;

  hipLaunchKernelGGL(enf_preA, dim3(195), dim3(256), 0, stream,
                     w3v, wv1, w2q, w3q, b2q, b3q,
                     ws + OFF_WGW, ws + OFF_U, ws + OFF_E);
  hipLaunchKernelGGL(enf_preB, dim3(260), dim3(256), 0, stream,
                     w2v, w3v, ws + OFF_WGW, ws + OFF_U, ws + OFF_E, wk, bk,
                     b2v, b3v, wv1, bv1, wv2, wout, bv2, bout,
                     ws + OFF_W2, ws + OFF_CB, ws + OFF_CGV, ws + OFF_WVOT,
                     ws + OFF_OUTC, ws + OFF_WQK, ws + OFF_KWCC);
  hipLaunchKernelGGL(enf_preC, dim3(224), dim3(256), 0, stream,
                     ws + OFF_W2, wv1,
                     (_Float16*)(ws + OFF_W2F), (_Float16*)(ws + OFF_WV1F));
  hipLaunchKernelGGL(enf_latent, dim3(B_*M_/8), dim3(256), 0, stream,
                     c, wvw, bv, ws + OFF_WQK, ws + OFF_KWCC, ws + OFF_CB, wv1,
                     ws + OFF_KW, ws + OFF_KB, ws + OFF_VF, ws + OFF_BASE);
  hipLaunchKernelGGL(enf_main, dim3(B_*N_), dim3(256), 0, stream,
                     x, p, g, w1q, w1v,
                     (const _Float16*)(ws + OFF_W2F), (const _Float16*)(ws + OFF_WV1F),
                     ws + OFF_CGV, ws + OFF_WVOT, ws + OFF_OUTC,
                     ws + OFF_KW, ws + OFF_KB, ws + OFF_VF, ws + OFF_BASE, outp);
}

// Round 7
// 383.480 us; speedup vs baseline: 1.0515x; 1.0515x over previous
//
#include <hip/hip_runtime.h>
#include <math.h>

#define B_ 4
#define N_ 2048
#define M_ 1024
#define K_ 32
#define HEADS_ 4
#define NH_ 128
#define PI_F 3.14159265358979323846f

typedef unsigned long long ull;
typedef __attribute__((ext_vector_type(8))) _Float16 half8;
typedef __attribute__((ext_vector_type(4))) _Float16 half4v;
typedef __attribute__((ext_vector_type(2))) _Float16 half2v;
typedef __attribute__((ext_vector_type(4))) float f32x4;

// workspace offsets (in floats)
#define OFF_WGW   0          // 16384
#define OFF_W2    16384      // 33280
#define OFF_CB    49664      // 128
#define OFF_CGV   49792      // 128
#define OFF_WVOT  49920      // 1536
#define OFF_OUTC  51456      // 4
#define OFF_KB    51460      // 16384
#define OFF_BASE  67844      // 524288 (fp32)
#define OFF_W2F   592132     // 20480 floats = 40960 halfs
#define OFF_WV1F  612612     // 8192 floats = 16384 halfs
#define OFF_U     620804     // 33280
#define OFF_E     654084     // 256
#define OFF_WQK   654340     // 67072
#define OFF_KWCC  721412     // 524
#define OFF_KWH   721936     // B*M*4*136 halfs = 2228224 halfs = 1114112 floats
#define OFF_VFH   1836048    // B*M*128 halfs = 524288 halfs = 262144 floats
// total = 2098192 floats (~8.4 MB)

// ---------- precompute stage A: WGW | U | E ----------
__global__ void enf_preA(const float* __restrict__ w3v, const float* __restrict__ wv1,
                         const float* __restrict__ w2q, const float* __restrict__ w3q,
                         const float* __restrict__ b2q, const float* __restrict__ b3q,
                         float* __restrict__ WGW, float* __restrict__ U,
                         float* __restrict__ E) {
  const int blk = blockIdx.x, tid = threadIdx.x;
  if (blk < 64) {
    int o = blk*256 + tid;
    int i = o >> 7, j = o & 127;
    float acc = 0.f;
    for (int r = 0; r < 128; ++r) acc = fmaf(w3v[i*256 + 128 + r], wv1[r*128 + j], acc);
    WGW[o] = acc;
  } else if (blk < 194) {
    int a = blk - 64, s = tid;
    float acc = 0.f;
    for (int i = 0; i < 128; ++i) acc = fmaf(w2q[a*128 + i], w3q[i*256 + s], acc);
    U[a*256 + s] = acc;
  } else {
    int s = tid;
    float acc = b3q[s];
    for (int j = 0; j < 128; ++j) acc = fmaf(b2q[j], w3q[j*256 + s], acc);
    E[s] = acc;
  }
}

// ---------- precompute stage B: W2 | consts | WQK | kwcc ----------
__global__ void enf_preB(const float* __restrict__ w2v, const float* __restrict__ w3v,
                         const float* __restrict__ WGW, const float* __restrict__ U,
                         const float* __restrict__ E, const float* __restrict__ wk,
                         const float* __restrict__ bk,
                         const float* __restrict__ b2v, const float* __restrict__ b3v,
                         const float* __restrict__ wv1, const float* __restrict__ bv1,
                         const float* __restrict__ wv2, const float* __restrict__ wout,
                         const float* __restrict__ bv2, const float* __restrict__ bout,
                         float* __restrict__ W2, float* __restrict__ cb,
                         float* __restrict__ cgv, float* __restrict__ wvoT,
                         float* __restrict__ outconst, float* __restrict__ WQK,
                         float* __restrict__ kwcc) {
  const int blk = blockIdx.x, t = threadIdx.x;
  if (blk < 130) {
    int a = blk, j = t;
    float acc = 0.f;
    if (j < 128) {
      for (int i = 0; i < 128; ++i) acc = fmaf(w2v[a*128 + i], w3v[i*256 + j], acc);
    } else {
      int j2 = j - 128;
      for (int i = 0; i < 128; ++i) acc = fmaf(w2v[a*128 + i], WGW[i*128 + j2], acc);
    }
    W2[a*256 + j] = acc;
  } else if (blk == 130) {
    if (t < 128) {
      float a1 = 0.f;
      for (int i = 0; i < 128; ++i) a1 = fmaf(b2v[i], w3v[i*256 + t], a1);
      cb[t] = a1 + b3v[t];
      float a2 = 0.f;
      for (int i = 0; i < 128; ++i) a2 = fmaf(b2v[i], WGW[i*128 + t], a2);
      for (int r = 0; r < 128; ++r) a2 = fmaf(b3v[128 + r], wv1[r*128 + t], a2);
      cgv[t] = a2 + bv1[t];
    }
    for (int o = t; o < 1536; o += 256) {
      int r12 = o >> 7, i = o & 127;
      int h = r12 / 3, c = r12 - h*3;
      float acc = 0.f;
      for (int k = 0; k < 128; ++k)
        acc = fmaf(wv2[i*512 + h*128 + k], wout[(h*128 + k)*3 + c], acc);
      wvoT[r12*128 + i] = acc;
    }
    if (t < 3) {
      float acc = bout[t];
      for (int r = 0; r < 512; ++r) acc = fmaf(bv2[r], wout[r*3 + t], acc);
      outconst[t] = acc;
    }
  } else if (blk < 259) {
    int l = blk - 131;
    for (int col = t; col < 524; col += 256) {
      float acc = 0.f;
      if (col < 520) {
        int h = col / 130, a = col - h*130;
        const float* ur = U + a*256 + h*64;
        const float* wr = wk + l*256 + h*64;
        for (int q = 0; q < 64; ++q) acc = fmaf(ur[q], wr[q], acc);
      } else {
        int h = col - 520;
        const float* er = E + h*64;
        const float* wr = wk + l*256 + h*64;
        for (int q = 0; q < 64; ++q) acc = fmaf(er[q], wr[q], acc);
      }
      WQK[l*524 + col] = acc;
    }
  } else {
    for (int col = t; col < 524; col += 256) {
      float acc = 0.f;
      if (col < 520) {
        int h = col / 130, a = col - h*130;
        const float* ur = U + a*256 + h*64;
        const float* br = bk + h*64;
        for (int q = 0; q < 64; ++q) acc = fmaf(ur[q], br[q], acc);
      } else {
        int h = col - 520;
        const float* er = E + h*64;
        const float* br = bk + h*64;
        for (int q = 0; q < 64; ++q) acc = fmaf(er[q], br[q], acc);
      }
      kwcc[col] = acc;
    }
  }
}

// ---------- precompute stage C: MFMA A-fragments ----------
__global__ void enf_preC(const float* __restrict__ W2, const float* __restrict__ wv1,
                         _Float16* __restrict__ W2f, _Float16* __restrict__ wv1f) {
  const int blk = blockIdx.x, tid = threadIdx.x;
  if (blk < 160) {
    int idx = blk*256 + tid;
    int i = idx & 7, lane = (idx >> 3) & 63;
    int rest = idx >> 9;
    int ks = rest % 5, mt = rest / 5;
    int k = ks*32 + ((lane >> 4) << 3) + i;
    int n = mt*16 + (lane & 15);
    W2f[idx] = (k < 130) ? (_Float16)W2[k*256 + n] : (_Float16)0.f;
  } else {
    int idx = (blk - 160)*256 + tid;
    int i = idx & 7, lane = (idx >> 3) & 63;
    int rest = idx >> 9;
    int ks = rest & 3, mt = rest >> 2;
    int k = ks*32 + ((lane >> 4) << 3) + i;
    int j = mt*16 + (lane & 15);
    wv1f[idx] = (_Float16)wv1[k*128 + j];
  }
}

// ---------- latent kernel: 8 latents per block; fp16 kw/vf outputs ----------
__global__ __launch_bounds__(256) void enf_latent(
    const float* __restrict__ c, const float* __restrict__ wvw,
    const float* __restrict__ bv, const float* __restrict__ WQK,
    const float* __restrict__ kwcc, const float* __restrict__ cb,
    const float* __restrict__ wv1,
    _Float16* __restrict__ kwh, float* __restrict__ kb,
    _Float16* __restrict__ vfh, float* __restrict__ base_o) {
  const int bm0 = blockIdx.x * 8;
  const int tid = threadIdx.x;
  __shared__ float cls[8][128];
  __shared__ float evs[8][128];
  for (int t = tid; t < 1024; t += 256) cls[t >> 7][t & 127] = c[(size_t)bm0*128 + t];
  __syncthreads();
  for (int col = tid; col < 652; col += 256) {
    float a[8];
#pragma unroll
    for (int i = 0; i < 8; ++i) a[i] = 0.f;
    if (col < 128) {
      for (int l = 0; l < 128; ++l) {
        float w = wvw[l*128 + col];
#pragma unroll
        for (int i = 0; i < 8; ++i) a[i] = fmaf(cls[i][l], w, a[i]);
      }
      float bvc = bv[col];
      float cbf = 1.f + cb[col];
#pragma unroll
      for (int i = 0; i < 8; ++i) {
        float v = a[i] + bvc;
        vfh[(size_t)(bm0 + i)*128 + col] = (_Float16)v;
        evs[i][col] = v*cbf;
      }
    } else {
      const float* wq = WQK + (col - 128);
      for (int l = 0; l < 128; ++l) {
        float w = wq[l*524];
#pragma unroll
        for (int i = 0; i < 8; ++i) a[i] = fmaf(cls[i][l], w, a[i]);
      }
      float cc = kwcc[col - 128];
      if (col < 648) {
        int h = (col - 128) / 130, aa = (col - 128) - h*130;
#pragma unroll
        for (int i = 0; i < 8; ++i)
          kwh[((size_t)(bm0 + i)*4 + h)*136 + aa] = (_Float16)(a[i] + cc);
      } else {
        int h = col - 648;
#pragma unroll
        for (int i = 0; i < 8; ++i)
          kb[(size_t)(bm0 + i)*4 + h] = a[i] + cc;
      }
    }
  }
  __syncthreads();
  {
    const int col = tid & 127, h4 = (tid >> 7) * 4;
    float a0 = 0.f, a1 = 0.f, a2 = 0.f, a3 = 0.f;
    for (int l = 0; l < 128; ++l) {
      float w = wv1[l*128 + col];
      a0 = fmaf(evs[h4 + 0][l], w, a0);
      a1 = fmaf(evs[h4 + 1][l], w, a1);
      a2 = fmaf(evs[h4 + 2][l], w, a2);
      a3 = fmaf(evs[h4 + 3][l], w, a3);
    }
    base_o[(size_t)(bm0 + h4 + 0)*128 + col] = a0;
    base_o[(size_t)(bm0 + h4 + 1)*128 + col] = a1;
    base_o[(size_t)(bm0 + h4 + 2)*128 + col] = a2;
    base_o[(size_t)(bm0 + h4 + 3)*128 + col] = a3;
  }
}

// sfv B-fragment position: [nt(2)][ks(5)][lane(64)][i(8)] halfs
__device__ __forceinline__ int fragpos(int k, int e) {
  return ((((e >> 4)*5 + (k >> 5))*64 + (((k >> 3) & 3) << 4) + (e & 15)) << 3) + (k & 7);
}

// ---------- main kernel: one block per (b,n), batch->XCD swizzled ----------
__global__ __launch_bounds__(256, 8) void enf_main(
    const float* __restrict__ x, const float* __restrict__ p,
    const float* __restrict__ g,
    const float* __restrict__ w1q, const float* __restrict__ w1v,
    const _Float16* __restrict__ w2f, const _Float16* __restrict__ wv1f,
    const float* __restrict__ cgv, const float* __restrict__ wvoT,
    const float* __restrict__ outconst,
    const _Float16* __restrict__ kwh, const float* __restrict__ kb,
    const _Float16* __restrict__ vfh, const float* __restrict__ base,
    float* __restrict__ out) {
  // batch->XCD affinity: XCD = wgid%8 serves exactly one batch (b = (bid&7)>>1)
  const int bid = blockIdx.x;
  const int bn = (((bid & 7) >> 1) << 11) | ((bid & 1) << 10) | (bid >> 3);
  const int b = bn >> 11;          // N = 2048
  const int tid = threadIdx.x;
  const int lane = tid & 63;
  const int wid = tid >> 6;

  // S timeline (bytes):
  //  phase1: sfq fp16 half2[65][32] @ [0,8320) | sfvB 5120 halfs @ [8320,18560)
  //  phase2: evlds half[32][136] @ [0,8704)    | gt fp16 [32][136] @ [8704,17408)
  //  phase3: poL fp32 [384] @ [0,1536)
  __shared__ alignas(16) float S[4640];
  __shared__ int   selm[K_];
  __shared__ float seld[K_];
  __shared__ float gkv[K_];
  __shared__ float bi0[K_], bi1[K_];
  __shared__ float logits_s[K_*HEADS_];
  __shared__ float hpart[HEADS_*4];

  float* candd = S;
  int*   candm = (int*)(S + 128);
  half2v* sfq2 = (half2v*)S;                 // [65][32] half2 words
  _Float16* sfvB = (_Float16*)(S + 2080);    // 5120 halfs
  _Float16* evlds = (_Float16*)S;            // [32][136]
  _Float16* gt_h  = (_Float16*)S + 4352;     // [32][136]
  float* poL   = S;                          // [32][12]

  const float x0 = x[bn*2 + 0];
  const float x1 = x[bn*2 + 1];
  const float2* pb2 = (const float2*)(p + (size_t)b*M_*2);

  // ---- Phase A: per-wave top-32 via binary-search threshold on float bits ----
  unsigned db[4]; int mm[4];
#pragma unroll
  for (int s = 0; s < 4; ++s) {
    int m = wid*256 + s*64 + lane;
    float2 pv = pb2[m];
    float d0 = x0 - pv.x, d1 = x1 - pv.y;
    float d = __fadd_rn(__fmul_rn(d0, d0), __fmul_rn(d1, d1));
    db[s] = __float_as_uint(d);
    mm[s] = m;
  }
  unsigned xth = 0;
  for (int bit = 30; bit >= 0; --bit) {
    unsigned trial = xth | (1u << bit);
    int cnt = __popcll(__ballot(db[0] < trial)) + __popcll(__ballot(db[1] < trial))
            + __popcll(__ballot(db[2] < trial)) + __popcll(__ballot(db[3] < trial));
    if (cnt < 32) xth = trial;
  }
  {
    ull bl[4], be[4];
#pragma unroll
    for (int s = 0; s < 4; ++s) {
      bl[s] = __ballot(db[s] < xth);
      be[s] = __ballot(db[s] == xth);
    }
    int r = __popcll(bl[0]) + __popcll(bl[1]) + __popcll(bl[2]) + __popcll(bl[3]);
    const ull lmask = (1ull << lane) - 1ull;
    int pl = 0, pe = 0;
#pragma unroll
    for (int s = 0; s < 4; ++s) {
      if (db[s] < xth) {
        int pos = pl + __popcll(bl[s] & lmask);
        candd[wid*K_ + pos] = __uint_as_float(db[s]);
        candm[wid*K_ + pos] = mm[s];
      } else if (db[s] == xth) {
        int pos = r + pe + __popcll(be[s] & lmask);
        if (pos < K_) {
          candd[wid*K_ + pos] = __uint_as_float(db[s]);
          candm[wid*K_ + pos] = mm[s];
        }
      }
      pl += __popcll(bl[s]);
      pe += __popcll(be[s]);
    }
  }
  __syncthreads();
  if (tid < 128) {
    float d = candd[tid];
    int m = candm[tid];
    int rank = 0;
    for (int i = 0; i < 128; ++i) {
      float di = candd[i];
      rank += (di < d || (di == d && i < tid)) ? 1 : 0;
    }
    if (rank < K_) { selm[rank] = m; seld[rank] = d; }
  }
  __syncthreads();
  if (tid < K_) {
    int m = selm[tid];
    gkv[tid] = g[(size_t)b*M_ + m];
    float2 pv = pb2[m];
    bi0[tid] = x0 - pv.x;
    bi1[tid] = x1 - pv.y;
  }
  __syncthreads();

  // ---- Phase B: sin features, sfq fp16 half2 words, sfv fp16 B-frags ----
  if (tid < 32) {
    const int e = tid;
    half2v h;
    h[0] = (_Float16)__sinf(bi0[e]);
    h[1] = (_Float16)__sinf(bi1[e]);
    sfq2[e] = h;                      // word 0: k=0,1
    sfvB[fragpos(0, e)] = h[0];
    sfvB[fragpos(1, e)] = h[1];
  }
  for (int t = tid; t < 960; t += 256) {      // zero-pad sfv frags k=130..159
    int k = 130 + (t >> 5), e = t & 31;
    sfvB[fragpos(k, e)] = (_Float16)0.f;
  }
  {
    const int e = tid & 31;
    const int jg = tid >> 5;           // 0..7
    const float s0 = PI_F*(bi0[e] + 1.f), s1 = PI_F*(bi1[e] + 1.f);
#pragma unroll
    for (int t4 = 0; t4 < 4; ++t4) {
      const int J = 2*jg + 16*t4;      // even, covers 0..62
      float eqa = s0*w1q[J]     + s1*w1q[64 + J];
      float eqb = s0*w1q[J + 1] + s1*w1q[64 + J + 1];
      float eva = s0*w1v[J]     + s1*w1v[64 + J];
      float evb = s0*w1v[J + 1] + s1*w1v[64 + J + 1];
      half2v hs, hc;
      hs[0] = (_Float16)__sinf(eqa); hs[1] = (_Float16)__sinf(eqb);
      hc[0] = (_Float16)__cosf(eqa); hc[1] = (_Float16)__cosf(eqb);
      sfq2[(1 + (J >> 1))*32 + e]  = hs;   // k = 2+J, 3+J
      sfq2[(33 + (J >> 1))*32 + e] = hc;   // k = 66+J, 67+J
      sfvB[fragpos(2 + J, e)]  = (_Float16)__sinf(eva);
      sfvB[fragpos(3 + J, e)]  = (_Float16)__sinf(evb);
      sfvB[fragpos(66 + J, e)] = (_Float16)__cosf(eva);
      sfvB[fragpos(67 + J, e)] = (_Float16)__cosf(evb);
    }
  }
  __syncthreads();

  // ---- Phase C: attention logits (waves 0,1); waves 2,3 start GEMM1 ----
  if (tid < 128) {
    const int e = tid >> 2, h = tid & 3;
    const int m = selm[e];
    const _Float16* kwrow = kwh + ((size_t)((b*M_ + m)*4 + h))*136;
    float accq = kb[(size_t)(b*M_ + m)*4 + h];
    const half8* kw8 = (const half8*)kwrow;
    const half2v* sq = sfq2 + e;
#pragma unroll 4
    for (int q8 = 0; q8 < 16; ++q8) {
      half8 kv = kw8[q8];
      half2v h0 = sq[(4*q8 + 0)*32];
      half2v h1 = sq[(4*q8 + 1)*32];
      half2v h2 = sq[(4*q8 + 2)*32];
      half2v h3 = sq[(4*q8 + 3)*32];
      accq = fmaf((float)h0[0], (float)kv[0], accq);
      accq = fmaf((float)h0[1], (float)kv[1], accq);
      accq = fmaf((float)h1[0], (float)kv[2], accq);
      accq = fmaf((float)h1[1], (float)kv[3], accq);
      accq = fmaf((float)h2[0], (float)kv[4], accq);
      accq = fmaf((float)h2[1], (float)kv[5], accq);
      accq = fmaf((float)h3[0], (float)kv[6], accq);
      accq = fmaf((float)h3[1], (float)kv[7], accq);
    }
    {
      half2v ht = sq[64*32];
      accq += (float)ht[0]*(float)kwrow[128] + (float)ht[1]*(float)kwrow[129];
    }
    const float gk = gkv[e];
    logits_s[tid] = accq - seld[e]/(gk*gk);
  }

  // ---- GEMM1 (MFMA): C1T = W2^T @ sfv^T
  f32x4 acc1[4][2];
#pragma unroll
  for (int mi = 0; mi < 4; ++mi)
#pragma unroll
    for (int nt = 0; nt < 2; ++nt) acc1[mi][nt] = (f32x4)0.f;
  {
    const half8* w2f8  = (const half8*)w2f;
    const half8* sfvB8 = (const half8*)sfvB;
#pragma unroll
    for (int ks = 0; ks < 5; ++ks) {
      half8 bf0 = sfvB8[(0*5 + ks)*64 + lane];
      half8 bf1 = sfvB8[(1*5 + ks)*64 + lane];
#pragma unroll
      for (int mi = 0; mi < 4; ++mi) {
        const int mt = (mi < 2) ? (2*wid + mi) : (8 + 2*wid + (mi - 2));
        half8 af = w2f8[(mt*5 + ks)*64 + lane];
        acc1[mi][0] = __builtin_amdgcn_mfma_f32_16x16x32_f16(af, bf0, acc1[mi][0], 0, 0, 0);
        acc1[mi][1] = __builtin_amdgcn_mfma_f32_16x16x32_f16(af, bf1, acc1[mi][1], 0, 0, 0);
      }
    }
  }
  __syncthreads();   // sfq + sfvB dead

  // ---- epilogue: evec (mi 0,1) -> evlds fp16; gterm (mi 2,3) -> registers ----
  f32x4 tg[2][2];
#pragma unroll
  for (int mi = 0; mi < 2; ++mi) {
    const int j0 = (2*wid + mi)*16 + ((lane >> 4) << 2);
#pragma unroll
    for (int nt = 0; nt < 2; ++nt) {
      const int e = nt*16 + (lane & 15);
      const half4v v4 = *(const half4v*)(vfh + ((size_t)(b*M_ + selm[e]))*NH_ + j0);
      f32x4 a = acc1[mi][nt];
      half4v hv;
      hv[0] = (_Float16)((float)v4[0] * a[0]);
      hv[1] = (_Float16)((float)v4[1] * a[1]);
      hv[2] = (_Float16)((float)v4[2] * a[2]);
      hv[3] = (_Float16)((float)v4[3] * a[3]);
      *(half4v*)(evlds + e*136 + j0) = hv;
    }
  }
#pragma unroll
  for (int mi = 0; mi < 2; ++mi) {
    const int j0 = 32*wid + mi*16 + ((lane >> 4) << 2);
    const float4 c4 = *(const float4*)(cgv + j0);
#pragma unroll
    for (int nt = 0; nt < 2; ++nt) {
      const int e = nt*16 + (lane & 15);
      const float4 b4 = *(const float4*)(base + ((size_t)(b*M_ + selm[e]))*NH_ + j0);
      f32x4 a = acc1[2 + mi][nt];
      tg[mi][nt][0] = a[0] + b4.x + c4.x;
      tg[mi][nt][1] = a[1] + b4.y + c4.y;
      tg[mi][nt][2] = a[2] + b4.z + c4.z;
      tg[mi][nt][3] = a[3] + b4.w + c4.w;
    }
  }
  __syncthreads();

  // ---- GEMM2 (MFMA): acc = tg + wv1^T @ ev^T ----
  {
    const half8* wv1f8 = (const half8*)wv1f;
    const half8* evB   = (const half8*)evlds;   // index: e*17 + ks*4 + (lane>>4)
#pragma unroll
    for (int ks = 0; ks < 4; ++ks) {
      half8 bf0 = evB[(lane & 15)*17 + ks*4 + (lane >> 4)];
      half8 bf1 = evB[(16 + (lane & 15))*17 + ks*4 + (lane >> 4)];
#pragma unroll
      for (int mi = 0; mi < 2; ++mi) {
        half8 af = wv1f8[((2*wid + mi)*4 + ks)*64 + lane];
        tg[mi][0] = __builtin_amdgcn_mfma_f32_16x16x32_f16(af, bf0, tg[mi][0], 0, 0, 0);
        tg[mi][1] = __builtin_amdgcn_mfma_f32_16x16x32_f16(af, bf1, tg[mi][1], 0, 0, 0);
      }
    }
  }
  // gelu epilogue -> gt fp16 (disjoint from evlds; no barrier needed)
#pragma unroll
  for (int mi = 0; mi < 2; ++mi) {
    const int j0 = (2*wid + mi)*16 + ((lane >> 4) << 2);
#pragma unroll
    for (int nt = 0; nt < 2; ++nt) {
      const int e = nt*16 + (lane & 15);
      f32x4 a = tg[mi][nt];
      half4v gv;
#pragma unroll
      for (int jj = 0; jj < 4; ++jj) {
        float tval = a[jj];
        float u = 0.79788456080286536f*(tval + 0.044715f*tval*tval*tval);
        float ex = __expf(2.f*u);
        float th = 1.f - 2.f/(ex + 1.f);
        gv[jj] = (_Float16)(0.5f*tval*(1.f + th));
      }
      *(half4v*)(gt_h + e*136 + j0) = gv;
    }
  }
  __syncthreads();

  // ---- Phase F: po[e][12] = gt[e] @ wvoT^T ----
  for (int t = tid; t < K_*12; t += 256) {
    const int e = t / 12, r = t - (t/12)*12;
    const float4* wr4 = (const float4*)(wvoT + r*NH_);
    const half8* gr8 = (const half8*)(gt_h + e*136);
    float a0 = 0.f, a1 = 0.f, a2 = 0.f, a3 = 0.f;
#pragma unroll 4
    for (int q = 0; q < 16; ++q) {
      half8 gq = gr8[q];
      float4 w0 = wr4[2*q], w1 = wr4[2*q + 1];
      a0 = fmaf((float)gq[0], w0.x, a0);
      a1 = fmaf((float)gq[1], w0.y, a1);
      a2 = fmaf((float)gq[2], w0.z, a2);
      a3 = fmaf((float)gq[3], w0.w, a3);
      a0 = fmaf((float)gq[4], w1.x, a0);
      a1 = fmaf((float)gq[5], w1.y, a1);
      a2 = fmaf((float)gq[6], w1.z, a2);
      a3 = fmaf((float)gq[7], w1.w, a3);
    }
    poL[t] = (a0 + a1) + (a2 + a3);
  }
  __syncthreads();

  // ---- Phase G: softmax over K per head + combine ----
  if (tid < 128) {
    const int h = tid >> 5, e = tid & 31;
    float l = logits_s[e*4 + h];
    float mx = l;
#pragma unroll
    for (int off = 1; off < 32; off <<= 1) mx = fmaxf(mx, __shfl_xor(mx, off));
    float w = __expf(l - mx);
    float s = w;
#pragma unroll
    for (int off = 1; off < 32; off <<= 1) s += __shfl_xor(s, off);
    float att = w / s;
    float p0 = att * poL[e*12 + h*3 + 0];
    float p1 = att * poL[e*12 + h*3 + 1];
    float p2 = att * poL[e*12 + h*3 + 2];
#pragma unroll
    for (int off = 1; off < 32; off <<= 1) {
      p0 += __shfl_xor(p0, off);
      p1 += __shfl_xor(p1, off);
      p2 += __shfl_xor(p2, off);
    }
    if (e == 0) { hpart[h*4 + 0] = p0; hpart[h*4 + 1] = p1; hpart[h*4 + 2] = p2; }
  }
  __syncthreads();
  if (tid < 3) {
    out[(size_t)bn*3 + tid] = outconst[tid]
        + hpart[0*4 + tid] + hpart[1*4 + tid] + hpart[2*4 + tid] + hpart[3*4 + tid];
  }
}

extern "C" void kernel_launch(void* const* d_in, const int* in_sizes, int n_in,
                              void* d_out, int out_size, void* d_ws, size_t ws_size,
                              hipStream_t stream) {
  (void)in_sizes; (void)n_in; (void)out_size; (void)ws_size;
  const float* x    = (const float*)d_in[0];
  const float* p    = (const float*)d_in[1];
  const float* c    = (const float*)d_in[2];
  const float* g    = (const float*)d_in[3];
  const float* w1q  = (const float*)d_in[4];
  const float* w2q  = (const float*)d_in[5];
  const float* b2q  = (const float*)d_in[6];
  const float* w3q  = (const float*)d_in[7];
  const float* b3q  = (const float*)d_in[8];
  const float* w1v  = (const float*)d_in[9];
  const float* w2v  = (const float*)d_in[10];
  const float* b2v  = (const float*)d_in[11];
  const float* w3v  = (const float*)d_in[12];
  const float* b3v  = (const float*)d_in[13];
  const float* wk   = (const float*)d_in[14];
  const float* bk   = (const float*)d_in[15];
  const float* wvw  = (const float*)d_in[16];
  const float* bv   = (const float*)d_in[17];
  const float* wv1  = (const float*)d_in[18];
  const float* bv1  = (const float*)d_in[19];
  const float* wv2  = (const float*)d_in[20];
  const float* bv2  = (const float*)d_in[21];
  const float* wout = (const float*)d_in[22];
  const float* bout = (const float*)d_in[23];
  float* ws = (float*)d_ws;
  float* outp = (float*)d_out;

  hipLaunchKernelGGL(enf_preA, dim3(195), dim3(256), 0, stream,
                     w3v, wv1, w2q, w3q, b2q, b3q,
                     ws + OFF_WGW, ws + OFF_U, ws + OFF_E);
  hipLaunchKernelGGL(enf_preB, dim3(260), dim3(256), 0, stream,
                     w2v, w3v, ws + OFF_WGW, ws + OFF_U, ws + OFF_E, wk, bk,
                     b2v, b3v, wv1, bv1, wv2, wout, bv2, bout,
                     ws + OFF_W2, ws + OFF_CB, ws + OFF_CGV, ws + OFF_WVOT,
                     ws + OFF_OUTC, ws + OFF_WQK, ws + OFF_KWCC);
  hipLaunchKernelGGL(enf_preC, dim3(224), dim3(256), 0, stream,
                     ws + OFF_W2, wv1,
                     (_Float16*)(ws + OFF_W2F), (_Float16*)(ws + OFF_WV1F));
  hipLaunchKernelGGL(enf_latent, dim3(B_*M_/8), dim3(256), 0, stream,
                     c, wvw, bv, ws + OFF_WQK, ws + OFF_KWCC, ws + OFF_CB, wv1,
                     (_Float16*)(ws + OFF_KWH), ws + OFF_KB,
                     (_Float16*)(ws + OFF_VFH), ws + OFF_BASE);
  hipLaunchKernelGGL(enf_main, dim3(B_*N_), dim3(256), 0, stream,
                     x, p, g, w1q, w1v,
                     (const _Float16*)(ws + OFF_W2F), (const _Float16*)(ws + OFF_WV1F),
                     ws + OFF_CGV, ws + OFF_WVOT, ws + OFF_OUTC,
                     (const _Float16*)(ws + OFF_KWH), ws + OFF_KB,
                     (const _Float16*)(ws + OFF_VFH), ws + OFF_BASE, outp);
}

// Round 8
// 313.116 us; speedup vs baseline: 1.2878x; 1.2247x over previous
//
#include <hip/hip_runtime.h>
#include <math.h>

#define B_ 4
#define N_ 2048
#define M_ 1024
#define K_ 32
#define HEADS_ 4
#define NH_ 128
#define PI_F 3.14159265358979323846f

typedef unsigned long long ull;
typedef __attribute__((ext_vector_type(8))) _Float16 half8;
typedef __attribute__((ext_vector_type(4))) _Float16 half4v;
typedef __attribute__((ext_vector_type(2))) _Float16 half2v;
typedef __attribute__((ext_vector_type(4))) float f32x4;

// workspace offsets (in floats)
#define OFF_WGW   0          // 16384
#define OFF_CB    16384      // 128
#define OFF_CGV   16512      // 128
#define OFF_WVOTH 16640      // 12*128 halfs = 768 floats
#define OFF_OUTC  17408      // 4
#define OFF_KB    17412      // 16384
#define OFF_BASE  33796      // 524288 (fp32)
#define OFF_W2F   558084     // 40960 halfs = 20480 floats
#define OFF_WV1F  578564     // 16384 halfs = 8192 floats
#define OFF_U     586756     // 33280
#define OFF_E     620036     // 256
#define OFF_WQK   620292     // 128*524 = 67072 (fp32)
#define OFF_KWCC  687364     // 524
#define OFF_KWH   687888     // B*M*4*136 halfs = 2228224 halfs = 1114112 floats
#define OFF_VFH   1802000    // B*M*128 halfs = 262144 floats
// total = 2064144 floats (~8.3 MB)

// W2f/wv1f fragment index for (k, n): [mt][ks][lane][i]
__device__ __host__ __forceinline__ int w2f_idx(int k, int n, int nks) {
  int mt = n >> 4, ks = k >> 5;
  int lane = (((k >> 3) & 3) << 4) | (n & 15);
  return (((mt*nks + ks)*64 + lane) << 3) + (k & 7);
}

// ---------- precompute stage A: WGW | U | E | wv1f ----------
__global__ void enf_preA(const float* __restrict__ w3v, const float* __restrict__ wv1,
                         const float* __restrict__ w2q, const float* __restrict__ w3q,
                         const float* __restrict__ b2q, const float* __restrict__ b3q,
                         float* __restrict__ WGW, float* __restrict__ U,
                         float* __restrict__ E, _Float16* __restrict__ wv1f) {
  const int blk = blockIdx.x, tid = threadIdx.x;
  if (blk < 64) {
    int o = blk*256 + tid;
    int i = o >> 7, j = o & 127;
    float acc = 0.f;
    for (int r = 0; r < 128; ++r) acc = fmaf(w3v[i*256 + 128 + r], wv1[r*128 + j], acc);
    WGW[o] = acc;
  } else if (blk < 194) {
    int a = blk - 64, s = tid;
    float acc = 0.f;
    for (int i = 0; i < 128; ++i) acc = fmaf(w2q[a*128 + i], w3q[i*256 + s], acc);
    U[a*256 + s] = acc;
  } else if (blk == 194) {
    int s = tid;
    float acc = b3q[s];
    for (int j = 0; j < 128; ++j) acc = fmaf(b2q[j], w3q[j*256 + s], acc);
    E[s] = acc;
  } else {                   // wv1f frags: [mt8][ks4][lane64][i8]
    int idx = (blk - 195)*256 + tid;
    int i = idx & 7, lane = (idx >> 3) & 63;
    int rest = idx >> 9;
    int ks = rest & 3, mt = rest >> 2;
    int k = ks*32 + ((lane >> 4) << 3) + i;
    int j = mt*16 + (lane & 15);
    wv1f[idx] = (_Float16)wv1[k*128 + j];
  }
}

// ---------- precompute stage B: W2f rows | consts+pad | WQK | kwcc ----------
__global__ void enf_preB(const float* __restrict__ w2v, const float* __restrict__ w3v,
                         const float* __restrict__ WGW, const float* __restrict__ U,
                         const float* __restrict__ E, const float* __restrict__ wk,
                         const float* __restrict__ bk,
                         const float* __restrict__ b2v, const float* __restrict__ b3v,
                         const float* __restrict__ wv1, const float* __restrict__ bv1,
                         const float* __restrict__ wv2, const float* __restrict__ wout,
                         const float* __restrict__ bv2, const float* __restrict__ bout,
                         _Float16* __restrict__ W2f, float* __restrict__ cb,
                         float* __restrict__ cgv, _Float16* __restrict__ wvoT_h,
                         float* __restrict__ outconst, float* __restrict__ WQK,
                         float* __restrict__ kwcc) {
  const int blk = blockIdx.x, t = threadIdx.x;
  if (blk < 130) {           // W2 row a -> fragment scatter (fp16)
    int a = blk, j = t;
    float acc = 0.f;
    if (j < 128) {
      for (int i = 0; i < 128; ++i) acc = fmaf(w2v[a*128 + i], w3v[i*256 + j], acc);
    } else {
      int j2 = j - 128;
      for (int i = 0; i < 128; ++i) acc = fmaf(w2v[a*128 + i], WGW[i*128 + j2], acc);
    }
    W2f[w2f_idx(a, j, 5)] = (_Float16)acc;
  } else if (blk == 130) {   // consts + W2f zero-pad k in [130,160)
    if (t < 128) {
      float a1 = 0.f;
      for (int i = 0; i < 128; ++i) a1 = fmaf(b2v[i], w3v[i*256 + t], a1);
      cb[t] = a1 + b3v[t];
      float a2 = 0.f;
      for (int i = 0; i < 128; ++i) a2 = fmaf(b2v[i], WGW[i*128 + t], a2);
      for (int r = 0; r < 128; ++r) a2 = fmaf(b3v[128 + r], wv1[r*128 + t], a2);
      cgv[t] = a2 + bv1[t];
    }
    for (int o = t; o < 1536; o += 256) {
      int r12 = o >> 7, i = o & 127;
      int h = r12 / 3, c = r12 - h*3;
      float acc = 0.f;
      for (int k = 0; k < 128; ++k)
        acc = fmaf(wv2[i*512 + h*128 + k], wout[(h*128 + k)*3 + c], acc);
      wvoT_h[r12*128 + i] = (_Float16)acc;
    }
    for (int o = t; o < 7680; o += 256) {
      int k = 130 + (o >> 8), n = o & 255;
      W2f[w2f_idx(k, n, 5)] = (_Float16)0.f;
    }
    if (t < 3) {
      float acc = bout[t];
      for (int r = 0; r < 512; ++r) acc = fmaf(bv2[r], wout[r*3 + t], acc);
      outconst[t] = acc;
    }
  } else if (blk < 259) {    // WQK row l
    int l = blk - 131;
    for (int col = t; col < 524; col += 256) {
      float acc = 0.f;
      if (col < 520) {
        int h = col / 130, a = col - h*130;
        const float* ur = U + a*256 + h*64;
        const float* wr = wk + l*256 + h*64;
        for (int q = 0; q < 64; ++q) acc = fmaf(ur[q], wr[q], acc);
      } else {
        int h = col - 520;
        const float* er = E + h*64;
        const float* wr = wk + l*256 + h*64;
        for (int q = 0; q < 64; ++q) acc = fmaf(er[q], wr[q], acc);
      }
      WQK[l*524 + col] = acc;
    }
  } else {                   // kwcc
    for (int col = t; col < 524; col += 256) {
      float acc = 0.f;
      if (col < 520) {
        int h = col / 130, a = col - h*130;
        const float* ur = U + a*256 + h*64;
        const float* br = bk + h*64;
        for (int q = 0; q < 64; ++q) acc = fmaf(ur[q], br[q], acc);
      } else {
        int h = col - 520;
        const float* er = E + h*64;
        const float* br = bk + h*64;
        for (int q = 0; q < 64; ++q) acc = fmaf(er[q], br[q], acc);
      }
      kwcc[col] = acc;
    }
  }
}

// ---------- latent kernel: 16 latents per block ----------
__global__ __launch_bounds__(256) void enf_latent(
    const float* __restrict__ c, const float* __restrict__ wvw,
    const float* __restrict__ bv, const float* __restrict__ WQK,
    const float* __restrict__ kwcc, const float* __restrict__ cb,
    const float* __restrict__ wv1,
    _Float16* __restrict__ kwh, float* __restrict__ kb,
    _Float16* __restrict__ vfh, float* __restrict__ base_o) {
  const int bm0 = blockIdx.x * 16;
  const int tid = threadIdx.x;
  __shared__ float cls[16][128];
  __shared__ float evs[16][128];
  for (int t = tid; t < 2048; t += 256) cls[t >> 7][t & 127] = c[(size_t)bm0*128 + t];
  __syncthreads();
  for (int col = tid; col < 652; col += 256) {
    float a[16];
#pragma unroll
    for (int i = 0; i < 16; ++i) a[i] = 0.f;
    if (col < 128) {
      for (int l = 0; l < 128; ++l) {
        float w = wvw[l*128 + col];
#pragma unroll
        for (int i = 0; i < 16; ++i) a[i] = fmaf(cls[i][l], w, a[i]);
      }
      float bvc = bv[col];
      float cbf = 1.f + cb[col];
#pragma unroll
      for (int i = 0; i < 16; ++i) {
        float v = a[i] + bvc;
        vfh[(size_t)(bm0 + i)*128 + col] = (_Float16)v;
        evs[i][col] = v*cbf;
      }
    } else {
      const float* wq = WQK + (col - 128);
      for (int l = 0; l < 128; ++l) {
        float w = wq[l*524];
#pragma unroll
        for (int i = 0; i < 16; ++i) a[i] = fmaf(cls[i][l], w, a[i]);
      }
      float cc = kwcc[col - 128];
      if (col < 648) {
        int h = (col - 128) / 130, aa = (col - 128) - h*130;
#pragma unroll
        for (int i = 0; i < 16; ++i)
          kwh[((size_t)(bm0 + i)*4 + h)*136 + aa] = (_Float16)(a[i] + cc);
      } else {
        int h = col - 648;
#pragma unroll
        for (int i = 0; i < 16; ++i)
          kb[(size_t)(bm0 + i)*4 + h] = a[i] + cc;
      }
    }
  }
  __syncthreads();
  {
    const int col = tid & 127, i0 = (tid >> 7) * 8;
    float bacc[8];
#pragma unroll
    for (int i = 0; i < 8; ++i) bacc[i] = 0.f;
    for (int l = 0; l < 128; ++l) {
      float w = wv1[l*128 + col];
#pragma unroll
      for (int i = 0; i < 8; ++i) bacc[i] = fmaf(evs[i0 + i][l], w, bacc[i]);
    }
#pragma unroll
    for (int i = 0; i < 8; ++i)
      base_o[(size_t)(bm0 + i0 + i)*128 + col] = bacc[i];
  }
}

// sfv B-fragment position: [nt(2)][ks(5)][lane(64)][i(8)] halfs
__device__ __forceinline__ int fragpos(int k, int e) {
  return ((((e >> 4)*5 + (k >> 5))*64 + (((k >> 3) & 3) << 4) + (e & 15)) << 3) + (k & 7);
}

// ---------- main kernel: one block per (b,n), batch->XCD swizzled ----------
__global__ __launch_bounds__(256, 8) void enf_main(
    const float* __restrict__ x, const float* __restrict__ p,
    const float* __restrict__ g,
    const float* __restrict__ w1q, const float* __restrict__ w1v,
    const _Float16* __restrict__ w2f, const _Float16* __restrict__ wv1f,
    const float* __restrict__ cgv, const _Float16* __restrict__ wvoT_h,
    const float* __restrict__ outconst,
    const _Float16* __restrict__ kwh, const float* __restrict__ kb,
    const _Float16* __restrict__ vfh, const float* __restrict__ base,
    float* __restrict__ out) {
  // batch->XCD affinity: XCD = wgid%8 serves exactly one batch (b = (bid&7)>>1)
  const int bid = blockIdx.x;
  const int bn = (((bid & 7) >> 1) << 11) | ((bid & 1) << 10) | (bid >> 3);
  const int b = bn >> 11;          // N = 2048
  const int tid = threadIdx.x;
  const int lane = tid & 63;
  const int wid = tid >> 6;

  __shared__ alignas(16) float S[4640];
  __shared__ int   selm[K_];
  __shared__ float seld[K_];
  __shared__ float gkv[K_];
  __shared__ float bi0[K_], bi1[K_];
  __shared__ float logits_s[K_*HEADS_];
  __shared__ float hpart[HEADS_*4];

  float* candd = S;
  int*   candm = (int*)(S + 128);
  half2v* sfq2 = (half2v*)S;                 // [65][32] half2 words
  _Float16* sfvB = (_Float16*)(S + 2080);    // 5120 halfs
  _Float16* evlds = (_Float16*)S;            // [32][136]
  _Float16* gt_h  = (_Float16*)S + 4352;     // [32][136]
  float* poL   = S;                          // [32][12]

  const float x0 = x[bn*2 + 0];
  const float x1 = x[bn*2 + 1];
  const float2* pb2 = (const float2*)(p + (size_t)b*M_*2);

  // ---- Phase A: per-wave top-32 via binary-search threshold on float bits ----
  unsigned db[4]; int mm[4];
#pragma unroll
  for (int s = 0; s < 4; ++s) {
    int m = wid*256 + s*64 + lane;
    float2 pv = pb2[m];
    float d0 = x0 - pv.x, d1 = x1 - pv.y;
    float d = __fadd_rn(__fmul_rn(d0, d0), __fmul_rn(d1, d1));
    db[s] = __float_as_uint(d);
    mm[s] = m;
  }
  unsigned xth = 0;
  for (int bit = 30; bit >= 0; --bit) {
    unsigned trial = xth | (1u << bit);
    int cnt = __popcll(__ballot(db[0] < trial)) + __popcll(__ballot(db[1] < trial))
            + __popcll(__ballot(db[2] < trial)) + __popcll(__ballot(db[3] < trial));
    if (cnt < 32) xth = trial;
  }
  {
    ull bl[4], be[4];
#pragma unroll
    for (int s = 0; s < 4; ++s) {
      bl[s] = __ballot(db[s] < xth);
      be[s] = __ballot(db[s] == xth);
    }
    int r = __popcll(bl[0]) + __popcll(bl[1]) + __popcll(bl[2]) + __popcll(bl[3]);
    const ull lmask = (1ull << lane) - 1ull;
    int pl = 0, pe = 0;
#pragma unroll
    for (int s = 0; s < 4; ++s) {
      if (db[s] < xth) {
        int pos = pl + __popcll(bl[s] & lmask);
        candd[wid*K_ + pos] = __uint_as_float(db[s]);
        candm[wid*K_ + pos] = mm[s];
      } else if (db[s] == xth) {
        int pos = r + pe + __popcll(be[s] & lmask);
        if (pos < K_) {
          candd[wid*K_ + pos] = __uint_as_float(db[s]);
          candm[wid*K_ + pos] = mm[s];
        }
      }
      pl += __popcll(bl[s]);
      pe += __popcll(be[s]);
    }
  }
  __syncthreads();
  // merge: rank + fill selm/seld/gkv/bi in one pass
  if (tid < 128) {
    float d = candd[tid];
    int m = candm[tid];
    int rank = 0;
    for (int i = 0; i < 128; ++i) {
      float di = candd[i];
      rank += (di < d || (di == d && i < tid)) ? 1 : 0;
    }
    if (rank < K_) {
      selm[rank] = m; seld[rank] = d;
      gkv[rank] = g[(size_t)b*M_ + m];
      float2 pv = pb2[m];
      bi0[rank] = x0 - pv.x;
      bi1[rank] = x1 - pv.y;
    }
  }
  __syncthreads();

  // ---- Phase B: sin features, sfq fp16 half2 words, sfv fp16 B-frags ----
  if (tid < 32) {
    const int e = tid;
    half2v h;
    h[0] = (_Float16)__sinf(bi0[e]);
    h[1] = (_Float16)__sinf(bi1[e]);
    sfq2[e] = h;                      // word 0: k=0,1
    sfvB[fragpos(0, e)] = h[0];
    sfvB[fragpos(1, e)] = h[1];
  }
  for (int t = tid; t < 960; t += 256) {      // zero-pad sfv frags k=130..159
    int k = 130 + (t >> 5), e = t & 31;
    sfvB[fragpos(k, e)] = (_Float16)0.f;
  }
  {
    const int e = tid & 31;
    const int jg = tid >> 5;           // 0..7
    const float s0 = PI_F*(bi0[e] + 1.f), s1 = PI_F*(bi1[e] + 1.f);
#pragma unroll
    for (int t4 = 0; t4 < 4; ++t4) {
      const int J = 2*jg + 16*t4;      // even, covers 0..62
      float eqa = s0*w1q[J]     + s1*w1q[64 + J];
      float eqb = s0*w1q[J + 1] + s1*w1q[64 + J + 1];
      float eva = s0*w1v[J]     + s1*w1v[64 + J];
      float evb = s0*w1v[J + 1] + s1*w1v[64 + J + 1];
      half2v hs, hc;
      hs[0] = (_Float16)__sinf(eqa); hs[1] = (_Float16)__sinf(eqb);
      hc[0] = (_Float16)__cosf(eqa); hc[1] = (_Float16)__cosf(eqb);
      sfq2[(1 + (J >> 1))*32 + e]  = hs;   // k = 2+J, 3+J
      sfq2[(33 + (J >> 1))*32 + e] = hc;   // k = 66+J, 67+J
      sfvB[fragpos(2 + J, e)]  = (_Float16)__sinf(eva);
      sfvB[fragpos(3 + J, e)]  = (_Float16)__sinf(evb);
      sfvB[fragpos(66 + J, e)] = (_Float16)__cosf(eva);
      sfvB[fragpos(67 + J, e)] = (_Float16)__cosf(evb);
    }
  }
  __syncthreads();

  // ---- Phase C: attention logits via v_dot2_f32_f16 (waves 0,1) ----
  if (tid < 128) {
    const int e = tid >> 2, h = tid & 3;
    const int m = selm[e];
    const _Float16* kwrow = kwh + ((size_t)((b*M_ + m)*4 + h))*136;
    float accq = kb[(size_t)(b*M_ + m)*4 + h];
    const half8* kw8 = (const half8*)kwrow;
    const half2v* sq = sfq2 + e;
#pragma unroll 4
    for (int q8 = 0; q8 < 16; ++q8) {
      half8 kv = kw8[q8];
      half2v k0; k0[0] = kv[0]; k0[1] = kv[1];
      half2v k1; k1[0] = kv[2]; k1[1] = kv[3];
      half2v k2; k2[0] = kv[4]; k2[1] = kv[5];
      half2v k3; k3[0] = kv[6]; k3[1] = kv[7];
      accq = __builtin_amdgcn_fdot2(sq[(4*q8 + 0)*32], k0, accq, false);
      accq = __builtin_amdgcn_fdot2(sq[(4*q8 + 1)*32], k1, accq, false);
      accq = __builtin_amdgcn_fdot2(sq[(4*q8 + 2)*32], k2, accq, false);
      accq = __builtin_amdgcn_fdot2(sq[(4*q8 + 3)*32], k3, accq, false);
    }
    {
      half2v kt = *(const half2v*)(kwrow + 128);
      accq = __builtin_amdgcn_fdot2(sq[64*32], kt, accq, false);
    }
    const float gk = gkv[e];
    logits_s[tid] = accq - seld[e]/(gk*gk);
  }

  // ---- GEMM1 (MFMA): C1T = W2^T @ sfv^T
  f32x4 acc1[4][2];
#pragma unroll
  for (int mi = 0; mi < 4; ++mi)
#pragma unroll
    for (int nt = 0; nt < 2; ++nt) acc1[mi][nt] = (f32x4)0.f;
  {
    const half8* w2f8  = (const half8*)w2f;
    const half8* sfvB8 = (const half8*)sfvB;
#pragma unroll
    for (int ks = 0; ks < 5; ++ks) {
      half8 bf0 = sfvB8[(0*5 + ks)*64 + lane];
      half8 bf1 = sfvB8[(1*5 + ks)*64 + lane];
#pragma unroll
      for (int mi = 0; mi < 4; ++mi) {
        const int mt = (mi < 2) ? (2*wid + mi) : (8 + 2*wid + (mi - 2));
        half8 af = w2f8[(mt*5 + ks)*64 + lane];
        acc1[mi][0] = __builtin_amdgcn_mfma_f32_16x16x32_f16(af, bf0, acc1[mi][0], 0, 0, 0);
        acc1[mi][1] = __builtin_amdgcn_mfma_f32_16x16x32_f16(af, bf1, acc1[mi][1], 0, 0, 0);
      }
    }
  }
  __syncthreads();   // sfq + sfvB dead

  // ---- epilogue: evec (mi 0,1) -> evlds fp16; gterm (mi 2,3) -> registers ----
  f32x4 tg[2][2];
#pragma unroll
  for (int mi = 0; mi < 2; ++mi) {
    const int j0 = (2*wid + mi)*16 + ((lane >> 4) << 2);
#pragma unroll
    for (int nt = 0; nt < 2; ++nt) {
      const int e = nt*16 + (lane & 15);
      const half4v v4 = *(const half4v*)(vfh + ((size_t)(b*M_ + selm[e]))*NH_ + j0);
      f32x4 a = acc1[mi][nt];
      half4v hv;
      hv[0] = (_Float16)((float)v4[0] * a[0]);
      hv[1] = (_Float16)((float)v4[1] * a[1]);
      hv[2] = (_Float16)((float)v4[2] * a[2]);
      hv[3] = (_Float16)((float)v4[3] * a[3]);
      *(half4v*)(evlds + e*136 + j0) = hv;
    }
  }
#pragma unroll
  for (int mi = 0; mi < 2; ++mi) {
    const int j0 = 32*wid + mi*16 + ((lane >> 4) << 2);
    const float4 c4 = *(const float4*)(cgv + j0);
#pragma unroll
    for (int nt = 0; nt < 2; ++nt) {
      const int e = nt*16 + (lane & 15);
      const float4 b4 = *(const float4*)(base + ((size_t)(b*M_ + selm[e]))*NH_ + j0);
      f32x4 a = acc1[2 + mi][nt];
      tg[mi][nt][0] = a[0] + b4.x + c4.x;
      tg[mi][nt][1] = a[1] + b4.y + c4.y;
      tg[mi][nt][2] = a[2] + b4.z + c4.z;
      tg[mi][nt][3] = a[3] + b4.w + c4.w;
    }
  }
  __syncthreads();

  // ---- GEMM2 (MFMA): acc = tg + wv1^T @ ev^T ----
  {
    const half8* wv1f8 = (const half8*)wv1f;
    const half8* evB   = (const half8*)evlds;   // index: e*17 + ks*4 + (lane>>4)
#pragma unroll
    for (int ks = 0; ks < 4; ++ks) {
      half8 bf0 = evB[(lane & 15)*17 + ks*4 + (lane >> 4)];
      half8 bf1 = evB[(16 + (lane & 15))*17 + ks*4 + (lane >> 4)];
#pragma unroll
      for (int mi = 0; mi < 2; ++mi) {
        half8 af = wv1f8[((2*wid + mi)*4 + ks)*64 + lane];
        tg[mi][0] = __builtin_amdgcn_mfma_f32_16x16x32_f16(af, bf0, tg[mi][0], 0, 0, 0);
        tg[mi][1] = __builtin_amdgcn_mfma_f32_16x16x32_f16(af, bf1, tg[mi][1], 0, 0, 0);
      }
    }
  }
  // gelu epilogue -> gt fp16 (disjoint from evlds; no barrier needed)
#pragma unroll
  for (int mi = 0; mi < 2; ++mi) {
    const int j0 = (2*wid + mi)*16 + ((lane >> 4) << 2);
#pragma unroll
    for (int nt = 0; nt < 2; ++nt) {
      const int e = nt*16 + (lane & 15);
      f32x4 a = tg[mi][nt];
      half4v gv;
#pragma unroll
      for (int jj = 0; jj < 4; ++jj) {
        float tval = a[jj];
        float u = 0.79788456080286536f*(tval + 0.044715f*tval*tval*tval);
        float ex = __expf(2.f*u);
        float th = 1.f - 2.f/(ex + 1.f);
        gv[jj] = (_Float16)(0.5f*tval*(1.f + th));
      }
      *(half4v*)(gt_h + e*136 + j0) = gv;
    }
  }
  __syncthreads();

  // ---- Phase F: po[e][12] = gt[e] @ wvoT^T via v_dot2_f32_f16 ----
  for (int t = tid; t < K_*12; t += 256) {
    const int e = t / 12, r = t - (t/12)*12;
    const half8* wr8 = (const half8*)(wvoT_h + r*NH_);
    const half8* gr8 = (const half8*)(gt_h + e*136);
    float a0 = 0.f, a1 = 0.f, a2 = 0.f, a3 = 0.f;
#pragma unroll 4
    for (int q = 0; q < 16; ++q) {
      half8 gq = gr8[q];
      half8 wq = wr8[q];
      half2v g0; g0[0] = gq[0]; g0[1] = gq[1];
      half2v g1; g1[0] = gq[2]; g1[1] = gq[3];
      half2v g2; g2[0] = gq[4]; g2[1] = gq[5];
      half2v g3; g3[0] = gq[6]; g3[1] = gq[7];
      half2v w0; w0[0] = wq[0]; w0[1] = wq[1];
      half2v w1; w1[0] = wq[2]; w1[1] = wq[3];
      half2v w2; w2[0] = wq[4]; w2[1] = wq[5];
      half2v w3; w3[0] = wq[6]; w3[1] = wq[7];
      a0 = __builtin_amdgcn_fdot2(g0, w0, a0, false);
      a1 = __builtin_amdgcn_fdot2(g1, w1, a1, false);
      a2 = __builtin_amdgcn_fdot2(g2, w2, a2, false);
      a3 = __builtin_amdgcn_fdot2(g3, w3, a3, false);
    }
    poL[t] = (a0 + a1) + (a2 + a3);
  }
  __syncthreads();

  // ---- Phase G: softmax over K per head + combine ----
  if (tid < 128) {
    const int h = tid >> 5, e = tid & 31;
    float l = logits_s[e*4 + h];
    float mx = l;
#pragma unroll
    for (int off = 1; off < 32; off <<= 1) mx = fmaxf(mx, __shfl_xor(mx, off));
    float w = __expf(l - mx);
    float s = w;
#pragma unroll
    for (int off = 1; off < 32; off <<= 1) s += __shfl_xor(s, off);
    float att = w / s;
    float p0 = att * poL[e*12 + h*3 + 0];
    float p1 = att * poL[e*12 + h*3 + 1];
    float p2 = att * poL[e*12 + h*3 + 2];
#pragma unroll
    for (int off = 1; off < 32; off <<= 1) {
      p0 += __shfl_xor(p0, off);
      p1 += __shfl_xor(p1, off);
      p2 += __shfl_xor(p2, off);
    }
    if (e == 0) { hpart[h*4 + 0] = p0; hpart[h*4 + 1] = p1; hpart[h*4 + 2] = p2; }
  }
  __syncthreads();
  if (tid < 3) {
    out[(size_t)bn*3 + tid] = outconst[tid]
        + hpart[0*4 + tid] + hpart[1*4 + tid] + hpart[2*4 + tid] + hpart[3*4 + tid];
  }
}

extern "C" void kernel_launch(void* const* d_in, const int* in_sizes, int n_in,
                              void* d_out, int out_size, void* d_ws, size_t ws_size,
                              hipStream_t stream) {
  (void)in_sizes; (void)n_in; (void)out_size; (void)ws_size;
  const float* x    = (const float*)d_in[0];
  const float* p    = (const float*)d_in[1];
  const float* c    = (const float*)d_in[2];
  const float* g    = (const float*)d_in[3];
  const float* w1q  = (const float*)d_in[4];
  const float* w2q  = (const float*)d_in[5];
  const float* b2q  = (const float*)d_in[6];
  const float* w3q  = (const float*)d_in[7];
  const float* b3q  = (const float*)d_in[8];
  const float* w1v  = (const float*)d_in[9];
  const float* w2v  = (const float*)d_in[10];
  const float* b2v  = (const float*)d_in[11];
  const float* w3v  = (const float*)d_in[12];
  const float* b3v  = (const float*)d_in[13];
  const float* wk   = (const float*)d_in[14];
  const float* bk   = (const float*)d_in[15];
  const float* wvw  = (const float*)d_in[16];
  const float* bv   = (const float*)d_in[17];
  const float* wv1  = (const float*)d_in[18];
  const float* bv1  = (const float*)d_in[19];
  const float* wv2  = (const float*)d_in[20];
  const float* bv2  = (const float*)d_in[21];
  const float* wout = (const float*)d_in[22];
  const float* bout = (const float*)d_in[23];
  float* ws = (float*)d_ws;
  float* outp = (float*)d_out;

  hipLaunchKernelGGL(enf_preA, dim3(259), dim3(256), 0, stream,
                     w3v, wv1, w2q, w3q, b2q, b3q,
                     ws + OFF_WGW, ws + OFF_U, ws + OFF_E,
                     (_Float16*)(ws + OFF_WV1F));
  hipLaunchKernelGGL(enf_preB, dim3(260), dim3(256), 0, stream,
                     w2v, w3v, ws + OFF_WGW, ws + OFF_U, ws + OFF_E, wk, bk,
                     b2v, b3v, wv1, bv1, wv2, wout, bv2, bout,
                     (_Float16*)(ws + OFF_W2F), ws + OFF_CB, ws + OFF_CGV,
                     (_Float16*)(ws + OFF_WVOTH),
                     ws + OFF_OUTC, ws + OFF_WQK, ws + OFF_KWCC);
  hipLaunchKernelGGL(enf_latent, dim3(B_*M_/16), dim3(256), 0, stream,
                     c, wvw, bv, ws + OFF_WQK, ws + OFF_KWCC, ws + OFF_CB, wv1,
                     (_Float16*)(ws + OFF_KWH), ws + OFF_KB,
                     (_Float16*)(ws + OFF_VFH), ws + OFF_BASE);
  hipLaunchKernelGGL(enf_main, dim3(B_*N_), dim3(256), 0, stream,
                     x, p, g, w1q, w1v,
                     (const _Float16*)(ws + OFF_W2F), (const _Float16*)(ws + OFF_WV1F),
                     ws + OFF_CGV, (const _Float16*)(ws + OFF_WVOTH), ws + OFF_OUTC,
                     (const _Float16*)(ws + OFF_KWH), ws + OFF_KB,
                     (const _Float16*)(ws + OFF_VFH), ws + OFF_BASE, outp);
}